// Round 5
// baseline (308.555 us; speedup 1.0000x reference)
//
#include <hip/hip_runtime.h>
#include <cstdint>
#include <cstddef>

// Problem constants
#define NUM_CODES 1024
#define DIM       256
#define NROWS     65536          // BATCH(8192) * NODE(8)
#define BM        64             // rows per block (64 -> 36KB LDS -> 4 blocks/CU)
#define LDS_STRIDE 264           // 256 + 8 pad (keeps 16B alignment, breaks bank conflicts)
#define OUT0_ELEMS 16777216      // 8192*8*256

typedef float v4f  __attribute__((ext_vector_type(4)));
typedef __bf16 v8bf __attribute__((ext_vector_type(8)));
typedef unsigned short v8us __attribute__((ext_vector_type(8)));
typedef unsigned short v4us __attribute__((ext_vector_type(4)));

__device__ inline unsigned short f2bf_rne(float f) {
  union { float f; unsigned u; } c; c.f = f;
  unsigned u = c.u;
  unsigned r = (u + 0x7FFFu + ((u >> 16) & 1u)) >> 16;
  return (unsigned short)r;
}

// One block per code k (1024 blocks, 256 threads = one per d).
__global__ __launch_bounds__(256) void vq_prep(const float* __restrict__ emb,
                                               unsigned short* __restrict__ eprep,
                                               float* __restrict__ e2,
                                               float* __restrict__ loss_slot) {
  const int k = blockIdx.x;
  const int d = threadIdx.x;
  float v = emb[k * DIM + d];

  float sq = v * v;
  #pragma unroll
  for (int off = 32; off; off >>= 1) sq += __shfl_down(sq, off);
  __shared__ float red[4];
  const int lane = threadIdx.x & 63, wv = threadIdx.x >> 6;
  if (lane == 0) red[wv] = sq;
  __syncthreads();
  if (threadIdx.x == 0) e2[k] = red[0] + red[1] + red[2] + red[3];
  if (blockIdx.x == 0 && threadIdx.x == 0) *loss_slot = 0.0f;

  // B-fragment layout for mfma_f32_16x16x32_bf16:
  // lane l holds B[kdim=(l>>4)*8+j][n=l&15]; tile = 16 codes (c16) x 32 d (kk)
  const int c16 = k >> 4;
  const int kk = d >> 5;
  const int quad = (d >> 3) & 3;
  const int j = d & 7;
  const int l = quad * 16 + (k & 15);
  eprep[(((c16 * 8 + kk) * 64) + l) * 8 + j] = f2bf_rne(v);
}

// 1024 blocks x 256 threads (4 waves = 4 code-groups, each covering all 64 rows).
// 4 blocks/CU (LDS ~36KB), whole grid co-resident -> eprep stays L2-hot after staging burst.
// launch_bounds(256,4): VGPR cap 128 — R4 showed (512,4)->64 VGPR causes scratch spill
// (FETCH 110->525MB, WRITE +81MB); ~100 live regs need the 128 budget.
__global__ __launch_bounds__(256, 4) void vq_main(const float* __restrict__ lat,
                                                  const float* __restrict__ emb,
                                                  const unsigned short* __restrict__ eprep,
                                                  const float* __restrict__ e2,
                                                  float* __restrict__ out,
                                                  float* __restrict__ loss_slot) {
  __shared__ __align__(16) unsigned short xlds[BM * LDS_STRIDE];
  __shared__ float rv[BM * 4];
  __shared__ int   ri[BM * 4];
  __shared__ int   fidx[BM];
  __shared__ float lred[4];

  const int tid = threadIdx.x;
  const int lane = tid & 63;
  const int cg = tid >> 6;           // wave 0..3 = code-group
  const int lane15 = lane & 15;
  const int quad = lane >> 4;
  const size_t rowbase_g = (size_t)blockIdx.x * BM;

  // ---- stage X tile: fp32 global -> bf16 LDS (read exactly once) ----
  const v4f* latv = (const v4f*)(lat + rowbase_g * DIM);
  #pragma unroll
  for (int i = 0; i < 16; ++i) {
    int g = i * 256 + tid;           // 4096 float4 per tile
    int row = g >> 6;                // 64 float4 per row
    int c4 = g & 63;
    v4f v = latv[g];
    v4us s;
    s.x = f2bf_rne(v.x); s.y = f2bf_rne(v.y);
    s.z = f2bf_rne(v.z); s.w = f2bf_rne(v.w);
    *(v4us*)(&xlds[row * LDS_STRIDE + c4 * 4]) = s;
  }
  __syncthreads();

  // ---- MFMA score tiles + running per-lane argmin ----
  float minv[16];
  int   mini[16];
  #pragma unroll
  for (int s = 0; s < 16; ++s) { minv[s] = 3.4e38f; mini[s] = 0; }

  const v8us* __restrict__ bptr = (const v8us*)eprep;

  for (int ct = 0; ct < 8; ++ct) {           // 8 code tiles of 128
    v4f acc[4][2] = {};
    const int cb = ct * 128 + cg * 32;       // wave's code base (32 codes)
    const int c16b = cb >> 4;

    #pragma unroll
    for (int kk = 0; kk < 8; ++kk) {         // D=256 in steps of 32
      v8bf a[4], b[2];
      #pragma unroll
      for (int nf = 0; nf < 2; ++nf)
        b[nf] = __builtin_bit_cast(v8bf, bptr[((c16b + nf) * 8 + kk) * 64 + lane]);
      #pragma unroll
      for (int mf = 0; mf < 4; ++mf) {
        const unsigned short* ap =
            &xlds[(mf * 16 + lane15) * LDS_STRIDE + kk * 32 + quad * 8];
        a[mf] = __builtin_bit_cast(v8bf, *(const v8us*)ap);
      }
      #pragma unroll
      for (int mf = 0; mf < 4; ++mf)
        #pragma unroll
        for (int nf = 0; nf < 2; ++nf)
          acc[mf][nf] = __builtin_amdgcn_mfma_f32_16x16x32_bf16(a[mf], b[nf], acc[mf][nf], 0, 0, 0);
    }

    // scores: s = ||e||^2 - 2*dot ; update running argmin
    // C/D layout: row = quad*4 + i, col = lane15
    #pragma unroll
    for (int nf = 0; nf < 2; ++nf) {
      const int code = cb + nf * 16 + lane15;
      const float e2v = e2[code];
      #pragma unroll
      for (int mf = 0; mf < 4; ++mf) {
        #pragma unroll
        for (int i = 0; i < 4; ++i) {
          float s = fmaf(-2.0f, acc[mf][nf][i], e2v);
          const int st = mf * 4 + i;
          if (s < minv[st]) { minv[st] = s; mini[st] = code; }
        }
      }
    }
  }

  // ---- argmin reduce across the 16 lanes sharing a quad ----
  #pragma unroll
  for (int s = 0; s < 16; ++s) {
    #pragma unroll
    for (int mask = 1; mask <= 8; mask <<= 1) {
      float ov = __shfl_xor(minv[s], mask);
      int   oi = __shfl_xor(mini[s], mask);
      if (ov < minv[s] || (ov == minv[s] && oi < mini[s])) { minv[s] = ov; mini[s] = oi; }
    }
  }
  if (lane15 == 0) {
    #pragma unroll
    for (int mf = 0; mf < 4; ++mf)
      #pragma unroll
      for (int i = 0; i < 4; ++i) {
        const int row = mf * 16 + quad * 4 + i;
        rv[row * 4 + cg] = minv[mf * 4 + i];
        ri[row * 4 + cg] = mini[mf * 4 + i];
      }
  }
  __syncthreads();
  if (tid < BM) {
    float bv = rv[tid * 4]; int bi = ri[tid * 4];
    #pragma unroll
    for (int c = 1; c < 4; ++c) {
      float v = rv[tid * 4 + c]; int ii = ri[tid * 4 + c];
      if (v < bv || (v == bv && ii < bi)) { bv = v; bi = ii; }
    }
    fidx[tid] = bi;
  }
  __syncthreads();

  // ---- epilogue: gather codebook rows (fp32, L2-hot), write out,
  // loss from the bf16 lat copy still in LDS (no HBM re-read; bias ~1e-6 << 2.5e-2) ----
  float partial = 0.0f;
  float* outg = out + rowbase_g * DIM;
  for (int r = 0; r < BM; ++r) {
    const int code = fidx[r];
    float ev = emb[code * DIM + tid];
    unsigned u = (unsigned)xlds[r * LDS_STRIDE + tid] << 16;
    float lv = __builtin_bit_cast(float, u);
    outg[(size_t)r * DIM + tid] = ev;
    float d = lv - ev;
    partial = fmaf(d, d, partial);
  }
  #pragma unroll
  for (int off = 32; off; off >>= 1) partial += __shfl_down(partial, off);
  if (lane == 0) lred[cg] = partial;
  __syncthreads();
  if (tid == 0)
    atomicAdd(loss_slot, (lred[0] + lred[1] + lred[2] + lred[3]) * (1.25f / 16777216.0f));
}

extern "C" void kernel_launch(void* const* d_in, const int* in_sizes, int n_in,
                              void* d_out, int out_size, void* d_ws, size_t ws_size,
                              hipStream_t stream) {
  const float* lat = (const float*)d_in[0];   // [8192, 2048] fp32
  const float* emb = (const float*)d_in[1];   // [1024, 256] fp32
  float* out = (float*)d_out;                 // [16777216] quantized_st + [1] vq_loss
  unsigned short* eprep = (unsigned short*)d_ws;                    // 512 KiB
  float* e2 = (float*)((char*)d_ws + NUM_CODES * DIM * sizeof(unsigned short));
  float* loss_slot = out + (size_t)OUT0_ELEMS;

  vq_prep<<<NUM_CODES, 256, 0, stream>>>(emb, eprep, e2, loss_slot);
  vq_main<<<NROWS / BM, 256, 0, stream>>>(lat, emb, eprep, e2, out, loss_slot);
}

// Round 6
// 169.169 us; speedup vs baseline: 1.8239x; 1.8239x over previous
//
#include <hip/hip_runtime.h>
#include <cstdint>
#include <cstddef>

// Problem constants
#define NUM_CODES 1024
#define DIM       256
#define NROWS     65536          // BATCH(8192) * NODE(8)
#define BM        64             // rows per block (~36KB LDS)
#define LDS_STRIDE 264           // 256 + 8 pad (keeps 16B alignment, breaks bank conflicts)
#define OUT0_ELEMS 16777216      // 8192*8*256

typedef float v4f  __attribute__((ext_vector_type(4)));
typedef __bf16 v8bf __attribute__((ext_vector_type(8)));
typedef unsigned short v8us __attribute__((ext_vector_type(8)));
typedef unsigned short v4us __attribute__((ext_vector_type(4)));

__device__ inline unsigned short f2bf_rne(float f) {
  union { float f; unsigned u; } c; c.f = f;
  unsigned u = c.u;
  unsigned r = (u + 0x7FFFu + ((u >> 16) & 1u)) >> 16;
  return (unsigned short)r;
}

// One block per code k (1024 blocks, 256 threads = one per d).
__global__ __launch_bounds__(256) void vq_prep(const float* __restrict__ emb,
                                               unsigned short* __restrict__ eprep,
                                               float* __restrict__ e2,
                                               float* __restrict__ loss_slot) {
  const int k = blockIdx.x;
  const int d = threadIdx.x;
  float v = emb[k * DIM + d];

  float sq = v * v;
  #pragma unroll
  for (int off = 32; off; off >>= 1) sq += __shfl_down(sq, off);
  __shared__ float red[4];
  const int lane = threadIdx.x & 63, wv = threadIdx.x >> 6;
  if (lane == 0) red[wv] = sq;
  __syncthreads();
  if (threadIdx.x == 0) e2[k] = red[0] + red[1] + red[2] + red[3];
  if (blockIdx.x == 0 && threadIdx.x == 0) *loss_slot = 0.0f;

  // B-fragment layout for mfma_f32_16x16x32_bf16:
  // lane l holds B[kdim=(l>>4)*8+j][n=l&15]; tile = 16 codes (c16) x 32 d (kk)
  const int c16 = k >> 4;
  const int kk = d >> 5;
  const int quad = (d >> 3) & 3;
  const int j = d & 7;
  const int l = quad * 16 + (k & 15);
  eprep[(((c16 * 8 + kk) * 64) + l) * 8 + j] = f2bf_rne(v);
}

// 1024 blocks x 256 threads (4 waves = 4 code-groups, each covering all 64 rows).
// __launch_bounds__(256, 2): 256 combined VGPR+AGPR budget/wave — R4/R5 showed that
// demanding 16 waves/CU (128-reg budget) forces arch-VGPR=64 + massive scratch spill
// (FETCH 110->528MB). With ~160 live regs/wave the HW still fits 3 blocks/CU = 12 waves.
__global__ __launch_bounds__(256, 2) void vq_main(const float* __restrict__ lat,
                                                  const float* __restrict__ emb,
                                                  const unsigned short* __restrict__ eprep,
                                                  const float* __restrict__ e2,
                                                  float* __restrict__ out,
                                                  float* __restrict__ loss_slot) {
  __shared__ __align__(16) unsigned short xlds[BM * LDS_STRIDE];
  __shared__ float rv[BM * 4];
  __shared__ int   ri[BM * 4];
  __shared__ int   fidx[BM];
  __shared__ float lred[4];

  const int tid = threadIdx.x;
  const int lane = tid & 63;
  const int cg = tid >> 6;           // wave 0..3 = code-group
  const int lane15 = lane & 15;
  const int quad = lane >> 4;
  const size_t rowbase_g = (size_t)blockIdx.x * BM;

  // ---- stage X tile: fp32 global -> bf16 LDS (read exactly once) ----
  const v4f* latv = (const v4f*)(lat + rowbase_g * DIM);
  #pragma unroll
  for (int i = 0; i < 16; ++i) {
    int g = i * 256 + tid;           // 4096 float4 per tile
    int row = g >> 6;                // 64 float4 per row
    int c4 = g & 63;
    v4f v = latv[g];
    v4us s;
    s.x = f2bf_rne(v.x); s.y = f2bf_rne(v.y);
    s.z = f2bf_rne(v.z); s.w = f2bf_rne(v.w);
    *(v4us*)(&xlds[row * LDS_STRIDE + c4 * 4]) = s;
  }
  __syncthreads();

  // ---- MFMA score tiles + running per-lane argmin ----
  float minv[16];
  int   mini[16];
  #pragma unroll
  for (int s = 0; s < 16; ++s) { minv[s] = 3.4e38f; mini[s] = 0; }

  const v8us* __restrict__ bptr = (const v8us*)eprep;

  for (int ct = 0; ct < 8; ++ct) {           // 8 code tiles of 128
    v4f acc[4][2] = {};
    const int cb = ct * 128 + cg * 32;       // wave's code base (32 codes)
    const int c16b = cb >> 4;

    #pragma unroll
    for (int kk = 0; kk < 8; ++kk) {         // D=256 in steps of 32
      v8bf a[4], b[2];
      #pragma unroll
      for (int nf = 0; nf < 2; ++nf)
        b[nf] = __builtin_bit_cast(v8bf, bptr[((c16b + nf) * 8 + kk) * 64 + lane]);
      #pragma unroll
      for (int mf = 0; mf < 4; ++mf) {
        const unsigned short* ap =
            &xlds[(mf * 16 + lane15) * LDS_STRIDE + kk * 32 + quad * 8];
        a[mf] = __builtin_bit_cast(v8bf, *(const v8us*)ap);
      }
      #pragma unroll
      for (int mf = 0; mf < 4; ++mf)
        #pragma unroll
        for (int nf = 0; nf < 2; ++nf)
          acc[mf][nf] = __builtin_amdgcn_mfma_f32_16x16x32_bf16(a[mf], b[nf], acc[mf][nf], 0, 0, 0);
    }

    // scores: s = ||e||^2 - 2*dot ; update running argmin
    // C/D layout: row = quad*4 + i, col = lane15
    #pragma unroll
    for (int nf = 0; nf < 2; ++nf) {
      const int code = cb + nf * 16 + lane15;
      const float e2v = e2[code];
      #pragma unroll
      for (int mf = 0; mf < 4; ++mf) {
        #pragma unroll
        for (int i = 0; i < 4; ++i) {
          float s = fmaf(-2.0f, acc[mf][nf][i], e2v);
          const int st = mf * 4 + i;
          if (s < minv[st]) { minv[st] = s; mini[st] = code; }
        }
      }
    }
  }

  // ---- argmin reduce across the 16 lanes sharing a quad ----
  #pragma unroll
  for (int s = 0; s < 16; ++s) {
    #pragma unroll
    for (int mask = 1; mask <= 8; mask <<= 1) {
      float ov = __shfl_xor(minv[s], mask);
      int   oi = __shfl_xor(mini[s], mask);
      if (ov < minv[s] || (ov == minv[s] && oi < mini[s])) { minv[s] = ov; mini[s] = oi; }
    }
  }
  if (lane15 == 0) {
    #pragma unroll
    for (int mf = 0; mf < 4; ++mf)
      #pragma unroll
      for (int i = 0; i < 4; ++i) {
        const int row = mf * 16 + quad * 4 + i;
        rv[row * 4 + cg] = minv[mf * 4 + i];
        ri[row * 4 + cg] = mini[mf * 4 + i];
      }
  }
  __syncthreads();
  if (tid < BM) {
    float bv = rv[tid * 4]; int bi = ri[tid * 4];
    #pragma unroll
    for (int c = 1; c < 4; ++c) {
      float v = rv[tid * 4 + c]; int ii = ri[tid * 4 + c];
      if (v < bv || (v == bv && ii < bi)) { bv = v; bi = ii; }
    }
    fidx[tid] = bi;
  }
  __syncthreads();

  // ---- epilogue (vectorized): wave cg owns rows cg*16..cg*16+15; lane handles
  // 4 consecutive floats (16B loads/stores). emb gather L2-hot; loss from the
  // bf16 lat copy in LDS (no HBM re-read; bias ~1e-6 << 2.5e-2 threshold) ----
  v4f partial4 = {0.0f, 0.0f, 0.0f, 0.0f};
  float* outg = out + rowbase_g * DIM;
  #pragma unroll 4
  for (int j = 0; j < 16; ++j) {
    const int r = cg * 16 + j;
    const int code = fidx[r];
    v4f ev = *(const v4f*)(emb + code * DIM + lane * 4);
    v4us ls = *(const v4us*)(&xlds[r * LDS_STRIDE + lane * 4]);
    v4f lv;
    lv.x = __builtin_bit_cast(float, (unsigned)ls.x << 16);
    lv.y = __builtin_bit_cast(float, (unsigned)ls.y << 16);
    lv.z = __builtin_bit_cast(float, (unsigned)ls.z << 16);
    lv.w = __builtin_bit_cast(float, (unsigned)ls.w << 16);
    *(v4f*)(outg + (size_t)r * DIM + lane * 4) = ev;
    v4f d = lv - ev;
    partial4 = d * d + partial4;
  }
  float partial = partial4.x + partial4.y + partial4.z + partial4.w;
  #pragma unroll
  for (int off = 32; off; off >>= 1) partial += __shfl_down(partial, off);
  if (lane == 0) lred[cg] = partial;
  __syncthreads();
  if (tid == 0)
    atomicAdd(loss_slot, (lred[0] + lred[1] + lred[2] + lred[3]) * (1.25f / 16777216.0f));
}

extern "C" void kernel_launch(void* const* d_in, const int* in_sizes, int n_in,
                              void* d_out, int out_size, void* d_ws, size_t ws_size,
                              hipStream_t stream) {
  const float* lat = (const float*)d_in[0];   // [8192, 2048] fp32
  const float* emb = (const float*)d_in[1];   // [1024, 256] fp32
  float* out = (float*)d_out;                 // [16777216] quantized_st + [1] vq_loss
  unsigned short* eprep = (unsigned short*)d_ws;                    // 512 KiB
  float* e2 = (float*)((char*)d_ws + NUM_CODES * DIM * sizeof(unsigned short));
  float* loss_slot = out + (size_t)OUT0_ELEMS;

  vq_prep<<<NUM_CODES, 256, 0, stream>>>(emb, eprep, e2, loss_slot);
  vq_main<<<NROWS / BM, 256, 0, stream>>>(lat, emb, eprep, e2, out, loss_slot);
}